// Round 3
// baseline (323.912 us; speedup 1.0000x reference)
//
#include <hip/hip_runtime.h>
#include <math.h>

#define B_ 8
#define T_ 2048
#define D_ 1024
#define H_ 128
#define BT (B_ * T_)

typedef short bf16x8 __attribute__((ext_vector_type(8)));
typedef float f32x4 __attribute__((ext_vector_type(4)));

static constexpr float SCALE = 0.08838834764831845f;  // 1/sqrt(128)

__device__ inline unsigned short f2b(float f) {
  unsigned int u = __float_as_uint(f);
  u += 0x7FFF + ((u >> 16) & 1);  // RNE
  return (unsigned short)(u >> 16);
}
__device__ inline unsigned int pk2(float a, float b) {
  return (unsigned int)f2b(a) | ((unsigned int)f2b(b) << 16);
}

// ---------------------------------------------------------------------------
// Setup: W[d][h] fp32 -> Wt[sel][h][d] bf16 (transposed). One-shot, tiny.
// ---------------------------------------------------------------------------
__global__ __launch_bounds__(256) void wcvt_kernel(
    const float* __restrict__ Wq, const float* __restrict__ Wk,
    const float* __restrict__ Wv, short* __restrict__ Wt) {
  const int sel = blockIdx.y;
  const float* W = sel == 0 ? Wq : (sel == 1 ? Wk : Wv);
  short* dst = Wt + (size_t)sel * D_ * H_;
  int slot = blockIdx.x * 256 + threadIdx.x;  // 32768 slots
  int d = slot >> 5, hg = slot & 31;
  float4 w = *(const float4*)(W + (size_t)d * H_ + hg * 4);
  dst[(size_t)(hg * 4 + 0) * D_ + d] = (short)f2b(w.x);
  dst[(size_t)(hg * 4 + 1) * D_ + d] = (short)f2b(w.y);
  dst[(size_t)(hg * 4 + 2) * D_ + d] = (short)f2b(w.z);
  dst[(size_t)(hg * 4 + 3) * D_ + d] = (short)f2b(w.w);
}

// ---------------------------------------------------------------------------
// Proj: C = X*W, bf16 MFMA, 64 rows x 128 cols per block (4 waves).
// Wave tile 32x64 (2x4 frags -> 12 ds_read : 16 MFMA). Register-prefetch
// double buffering: next K-tile's global loads fly during current compute.
// sel 0->q, 1->k (bf16 row-major), 2->v transposed to vt[b][h][t].
// ---------------------------------------------------------------------------
__global__ __launch_bounds__(256) void proj_kernel(
    const float* __restrict__ x, const short* __restrict__ Wt,
    short* __restrict__ qb, short* __restrict__ kb, short* __restrict__ vtb) {
  __shared__ alignas(16) char smem[27648];
  short* Xs = (short*)smem;           // [64][72] bf16
  short* Ws = (short*)(smem + 9216);  // [128][72] bf16

  const int tid = threadIdx.x;
  const int wave = tid >> 6, lane = tid & 63;
  const int ln = lane & 15, quad = lane >> 4;
  const int mw = wave & 1, nw = wave >> 1;  // wave -> 32-row, 64-col subtile
  const int sel = blockIdx.y;
  const int row0 = blockIdx.x * 64;
  const short* W = Wt + (size_t)sel * (size_t)(D_ * H_);

  f32x4 acc[2][4];
#pragma unroll
  for (int mi = 0; mi < 2; ++mi)
#pragma unroll
    for (int nt = 0; nt < 4; ++nt) acc[mi][nt] = (f32x4){0.f, 0.f, 0.f, 0.f};

  float4 xr[4];  // X prefetch: 64x64 fp32 tile, 4 float4/thread
  int4 wr[4];    // W prefetch: 128x64 bf16 tile, 4 int4/thread

#pragma unroll
  for (int i = 0; i < 4; ++i) {  // prefetch k0 = 0
    int slot = tid + i * 256;
    int r = slot >> 4, g = slot & 15;
    xr[i] = *(const float4*)(x + (size_t)(row0 + r) * D_ + g * 4);
    int n = slot >> 3, gw = slot & 7;
    wr[i] = *(const int4*)(W + (size_t)n * D_ + gw * 8);
  }

  for (int s = 0; s < 16; ++s) {
    if (s) __syncthreads();  // LDS free (prev compute done)
    // store prefetched regs -> LDS (X packed to bf16)
#pragma unroll
    for (int i = 0; i < 4; ++i) {
      int slot = tid + i * 256;
      int r = slot >> 4, g = slot & 15;
      unsigned int* p = (unsigned int*)&Xs[r * 72 + g * 4];
      p[0] = pk2(xr[i].x, xr[i].y);
      p[1] = pk2(xr[i].z, xr[i].w);
      int n = slot >> 3, gw = slot & 7;
      *(int4*)&Ws[n * 72 + gw * 8] = wr[i];
    }
    // issue next tile's loads; they complete during compute below
    if (s < 15) {
      const int k0 = (s + 1) * 64;
#pragma unroll
      for (int i = 0; i < 4; ++i) {
        int slot = tid + i * 256;
        int r = slot >> 4, g = slot & 15;
        xr[i] = *(const float4*)(x + (size_t)(row0 + r) * D_ + k0 + g * 4);
        int n = slot >> 3, gw = slot & 7;
        wr[i] = *(const int4*)(W + (size_t)n * D_ + k0 + gw * 8);
      }
    }
    __syncthreads();

#pragma unroll
    for (int kk = 0; kk < 2; ++kk) {
      bf16x8 a[2];
#pragma unroll
      for (int mi = 0; mi < 2; ++mi)
        a[mi] = *(bf16x8*)&Xs[(mw * 32 + mi * 16 + ln) * 72 + kk * 32 + quad * 8];
#pragma unroll
      for (int nt = 0; nt < 4; ++nt) {
        bf16x8 bb = *(bf16x8*)&Ws[(nw * 64 + nt * 16 + ln) * 72 + kk * 32 + quad * 8];
#pragma unroll
        for (int mi = 0; mi < 2; ++mi)
          acc[mi][nt] = __builtin_amdgcn_mfma_f32_16x16x32_bf16(a[mi], bb, acc[mi][nt], 0, 0, 0);
      }
    }
  }

  __syncthreads();  // done with Xs/Ws; reuse smem for epilogue repack
  short* Cs = (short*)smem;
  if (sel < 2) {
    short* out = sel ? kb : qb;
    // frags -> Cs[64][136] row-major
#pragma unroll
    for (int mi = 0; mi < 2; ++mi)
#pragma unroll
      for (int nt = 0; nt < 4; ++nt)
#pragma unroll
        for (int rr = 0; rr < 4; ++rr)
          Cs[(mw * 32 + mi * 16 + quad * 4 + rr) * 136 + nw * 64 + nt * 16 + ln] =
              (short)f2b(acc[mi][nt][rr]);
    __syncthreads();
#pragma unroll
    for (int i = 0; i < 4; ++i) {
      int slot = tid + i * 256;  // 1024 int4 slots = 64 rows x 16 groups
      int r = slot >> 4, g = slot & 15;
      *(int4*)(out + (size_t)(row0 + r) * H_ + g * 8) = *(int4*)&Cs[r * 136 + g * 8];
    }
  } else {
    // transpose through LDS, write vt[b][h][t] coalesced
#pragma unroll
    for (int mi = 0; mi < 2; ++mi)
#pragma unroll
      for (int nt = 0; nt < 4; ++nt)
#pragma unroll
        for (int rr = 0; rr < 4; ++rr)
          Cs[(nw * 64 + nt * 16 + ln) * 72 + mw * 32 + mi * 16 + quad * 4 + rr] =
              (short)f2b(acc[mi][nt][rr]);
    __syncthreads();
    const int b = row0 >> 11, t0 = row0 & 2047;
#pragma unroll
    for (int i = 0; i < 4; ++i) {
      int slot = tid + i * 256;  // 1024 int4 slots = 128 h x 8 groups
      int h = slot >> 3, g = slot & 7;
      *(int4*)(vtb + (size_t)(b * H_ + h) * T_ + t0 + g * 8) = *(int4*)&Cs[h * 72 + g * 8];
    }
  }
}

// ---------------------------------------------------------------------------
// Attention: flash-style MFMA, 32 queries/block, 64-key chunks, with the same
// register-prefetch: next chunk's K/V loads issued before current compute.
// ---------------------------------------------------------------------------
__global__ __launch_bounds__(256) void attn_kernel(
    const short* __restrict__ qb, const short* __restrict__ kb,
    const short* __restrict__ vtb, float* __restrict__ out) {
  __shared__ alignas(16) short Ks[64 * 136];   // [64][136] (+8 pad)
  __shared__ alignas(16) short Vt[128 * 72];   // [128][72] (+8 pad)
  __shared__ alignas(16) float Sf[32 * 65];    // [32][65] f32
  __shared__ alignas(16) short P[32 * 72];     // [32][72] bf16
  __shared__ float aA[32], lL[32];

  const int tid = threadIdx.x;
  const int wave = tid >> 6, lane = tid & 63;
  const int ln = lane & 15, quad = lane >> 4;
  const int b = blockIdx.x >> 6;
  const int tile = 63 - (blockIdx.x & 63);  // heavy tiles first
  const int q0 = tile * 32;

  bf16x8 qfr[2][4];  // Q frags resident in registers
#pragma unroll
  for (int m = 0; m < 2; ++m)
#pragma unroll
    for (int kk = 0; kk < 4; ++kk)
      qfr[m][kk] = *(const bf16x8*)(qb + (size_t)(b * T_ + q0 + m * 16 + ln) * H_ +
                                    kk * 32 + quad * 8);

  f32x4 oacc[2][2];
#pragma unroll
  for (int m = 0; m < 2; ++m)
#pragma unroll
    for (int nt = 0; nt < 2; ++nt) oacc[m][nt] = (f32x4){0.f, 0.f, 0.f, 0.f};

  const int srow = tid >> 3, l8 = tid & 7;
  float m_run = -INFINITY, l_run = 0.f;

  int4 kr[4], vr[4];  // prefetch regs: 16 KB K + 16 KB V^T per chunk
#pragma unroll
  for (int i = 0; i < 4; ++i) {  // prefetch chunk 0
    int slot = tid + i * 256;
    int r = slot >> 4, g = slot & 15;
    kr[i] = *(const int4*)(kb + (size_t)(b * T_ + r) * H_ + g * 8);
    int h = slot >> 3, g2 = slot & 7;
    vr[i] = *(const int4*)(vtb + (size_t)(b * H_ + h) * T_ + g2 * 8);
  }

  const int nch = ((q0 + 31) >> 6) + 1;
  for (int ch = 0; ch < nch; ++ch) {
    const int s0 = ch * 64;
    if (ch) __syncthreads();  // prev QK^T/PV done reading Ks/Vt
#pragma unroll
    for (int i = 0; i < 4; ++i) {
      int slot = tid + i * 256;
      int r = slot >> 4, g = slot & 15;
      *(int4*)&Ks[r * 136 + g * 8] = kr[i];
      int h = slot >> 3, g2 = slot & 7;
      *(int4*)&Vt[h * 72 + g2 * 8] = vr[i];
    }
    if (ch + 1 < nch) {  // issue next chunk's loads; fly during compute
      const int sn = s0 + 64;
#pragma unroll
      for (int i = 0; i < 4; ++i) {
        int slot = tid + i * 256;
        int r = slot >> 4, g = slot & 15;
        kr[i] = *(const int4*)(kb + (size_t)(b * T_ + sn + r) * H_ + g * 8);
        int h = slot >> 3, g2 = slot & 7;
        vr[i] = *(const int4*)(vtb + (size_t)(b * H_ + h) * T_ + sn + g2 * 8);
      }
    }
    __syncthreads();

    // S = Q K^T : each wave 32 queries x 16 keys
    f32x4 sacc[2];
    sacc[0] = (f32x4){0.f, 0.f, 0.f, 0.f};
    sacc[1] = (f32x4){0.f, 0.f, 0.f, 0.f};
#pragma unroll
    for (int kk = 0; kk < 4; ++kk) {
      bf16x8 bk = *(bf16x8*)&Ks[(wave * 16 + ln) * 136 + kk * 32 + quad * 8];
#pragma unroll
      for (int m = 0; m < 2; ++m)
        sacc[m] = __builtin_amdgcn_mfma_f32_16x16x32_bf16(qfr[m][kk], bk, sacc[m], 0, 0, 0);
    }
#pragma unroll
    for (int m = 0; m < 2; ++m)
#pragma unroll
      for (int r = 0; r < 4; ++r)
        Sf[(m * 16 + quad * 4 + r) * 65 + wave * 16 + ln] = sacc[m][r];
    __syncthreads();

    // online softmax: 8 lanes per row
    float sv[8];
    const int qg = q0 + srow;
#pragma unroll
    for (int i = 0; i < 8; ++i) {
      float s = Sf[srow * 65 + l8 * 8 + i] * SCALE;
      sv[i] = (s0 + l8 * 8 + i <= qg) ? s : -INFINITY;
    }
    float mx = sv[0];
#pragma unroll
    for (int i = 1; i < 8; ++i) mx = fmaxf(mx, sv[i]);
    mx = fmaxf(mx, __shfl_xor(mx, 1));
    mx = fmaxf(mx, __shfl_xor(mx, 2));
    mx = fmaxf(mx, __shfl_xor(mx, 4));
    const float mnew = fmaxf(m_run, mx);
    const float alpha = __expf(m_run - mnew);
    float p[8], ps = 0.f;
#pragma unroll
    for (int i = 0; i < 8; ++i) {
      p[i] = __expf(sv[i] - mnew);
      ps += p[i];
    }
    ps += __shfl_xor(ps, 1);
    ps += __shfl_xor(ps, 2);
    ps += __shfl_xor(ps, 4);
    l_run = l_run * alpha + ps;
    m_run = mnew;
    int4 pw;
    pw.x = (int)pk2(p[0], p[1]);
    pw.y = (int)pk2(p[2], p[3]);
    pw.z = (int)pk2(p[4], p[5]);
    pw.w = (int)pk2(p[6], p[7]);
    *(int4*)&P[srow * 72 + l8 * 8] = pw;
    if (l8 == 0) aA[srow] = alpha;
    __syncthreads();

    // O = O*alpha + P V : each wave 32 queries x 32 head-dims
    const int h0 = wave * 32;
    float ar[2][4];
#pragma unroll
    for (int m = 0; m < 2; ++m)
#pragma unroll
      for (int r = 0; r < 4; ++r) ar[m][r] = aA[m * 16 + quad * 4 + r];
#pragma unroll
    for (int m = 0; m < 2; ++m)
#pragma unroll
      for (int nt = 0; nt < 2; ++nt)
#pragma unroll
        for (int r = 0; r < 4; ++r) oacc[m][nt][r] *= ar[m][r];
#pragma unroll
    for (int ks = 0; ks < 2; ++ks) {
      bf16x8 pa[2];
      pa[0] = *(bf16x8*)&P[ln * 72 + ks * 32 + quad * 8];
      pa[1] = *(bf16x8*)&P[(16 + ln) * 72 + ks * 32 + quad * 8];
#pragma unroll
      for (int nt = 0; nt < 2; ++nt) {
        bf16x8 bv = *(bf16x8*)&Vt[(h0 + nt * 16 + ln) * 72 + ks * 32 + quad * 8];
#pragma unroll
        for (int m = 0; m < 2; ++m)
          oacc[m][nt] = __builtin_amdgcn_mfma_f32_16x16x32_bf16(pa[m], bv, oacc[m][nt], 0, 0, 0);
      }
    }
  }

  if (l8 == 0) lL[srow] = l_run;
  __syncthreads();
  const int h0 = wave * 32;
#pragma unroll
  for (int m = 0; m < 2; ++m) {
    float linv[4];
#pragma unroll
    for (int r = 0; r < 4; ++r) linv[r] = 1.f / lL[m * 16 + quad * 4 + r];
#pragma unroll
    for (int nt = 0; nt < 2; ++nt)
#pragma unroll
      for (int r = 0; r < 4; ++r) {
        int row = q0 + m * 16 + quad * 4 + r;
        out[(size_t)(b * T_ + row) * H_ + h0 + nt * 16 + ln] = oacc[m][nt][r] * linv[r];
      }
  }
}

// ---------------------------------------------------------------------------
extern "C" void kernel_launch(void* const* d_in, const int* in_sizes, int n_in,
                              void* d_out, int out_size, void* d_ws, size_t ws_size,
                              hipStream_t stream) {
  const float* x  = (const float*)d_in[0];
  const float* Wq = (const float*)d_in[1];
  const float* Wk = (const float*)d_in[2];
  const float* Wv = (const float*)d_in[3];
  float* out = (float*)d_out;

  char* ws = (char*)d_ws;
  short* qb  = (short*)(ws);                // 4 MB  q  bf16 [BT][128]
  short* kb  = (short*)(ws + 4194304);      // 4 MB  k  bf16 [BT][128]
  short* vtb = (short*)(ws + 8388608);      // 4 MB  v^T bf16 [B][128][T]
  short* Wt  = (short*)(ws + 12582912);     // 0.75 MB  W^T bf16 [3][128][1024]

  wcvt_kernel<<<dim3(128, 3), 256, 0, stream>>>(Wq, Wk, Wv, Wt);
  proj_kernel<<<dim3(BT / 64, 3), 256, 0, stream>>>(x, Wt, qb, kb, vtb);
  attn_kernel<<<dim3(8 * 64), 256, 0, stream>>>(qb, kb, vtb, out);
}